// Round 8
// baseline (416.288 us; speedup 1.0000x reference)
//
#include <hip/hip_runtime.h>
#include <stdint.h>

#define N_ROWS 4096
#define Z_DIM  2048
#define TOT    8192           // 2N rows of reps
#define TILE   128
#define RBYTES (Z_DIM / 2)    // 1024 B per fp4 row
#define BKE    128            // K elements per iteration
#define KBYT   (BKE / 2)      // 64 B per row per iteration
#define NITER  (Z_DIM / BKE)  // 16
#define NT     (TOT / TILE)   // 64 tile-columns
#define NBLK   (NT * (NT + 1) / 2)   // 2080 triangular blocks
#define INV_T  2.0f           // 1/temperature
#define SCL4   64.0f          // fp4 pre-scale; logits = acc * INV_T / SCL4^2

typedef __attribute__((ext_vector_type(4))) int   intx4;
typedef __attribute__((ext_vector_type(8))) int   intx8;
typedef __attribute__((ext_vector_type(4))) float floatx4;

// branchless f32 -> fp4 e2m1 code (round to nearest level)
// levels: 0,0.5,1,1.5,2,3,4,6 ; thresholds at midpoints
__device__ __forceinline__ unsigned int f2fp4(float v) {
    float a = fabsf(v);
    unsigned int c = (a >= 0.25f) + (a >= 0.75f) + (a >= 1.25f) + (a >= 1.75f)
                   + (a >= 2.5f)  + (a >= 3.5f)  + (a >= 5.0f);
    return c | (v < 0.f ? 8u : 0u);
}

// ---------------- kernel 1: row-normalize to fp4(e2m1, x64), pos, zero state
__global__ __launch_bounds__(256) void normalize_kernel(
    const float* __restrict__ z1, const float* __restrict__ z2,
    unsigned char* __restrict__ reps, float* __restrict__ pos,
    float* __restrict__ rowsum, int* __restrict__ counter)
{
    const int row  = blockIdx.x;          // 0..4095
    const int tid  = threadIdx.x;         // 0..255, 8 floats each
    const int lane = tid & 63, wave = tid >> 6;

    if (row < TOT / 256) rowsum[row * 256 + tid] = 0.f;   // fold in memset
    if (row == 0 && tid == 0) *counter = 0;

    const float4* p1 = (const float4*)(z1 + (size_t)row * Z_DIM);
    const float4* p2 = (const float4*)(z2 + (size_t)row * Z_DIM);
    float4 x0 = p1[tid * 2], x1 = p1[tid * 2 + 1];
    float4 y0 = p2[tid * 2], y1 = p2[tid * 2 + 1];

    float s1 = x0.x*x0.x + x0.y*x0.y + x0.z*x0.z + x0.w*x0.w
             + x1.x*x1.x + x1.y*x1.y + x1.z*x1.z + x1.w*x1.w;
    float s2 = y0.x*y0.x + y0.y*y0.y + y0.z*y0.z + y0.w*y0.w
             + y1.x*y1.x + y1.y*y1.y + y1.z*y1.z + y1.w*y1.w;
    float dd = x0.x*y0.x + x0.y*y0.y + x0.z*y0.z + x0.w*y0.w
             + x1.x*y1.x + x1.y*y1.y + x1.z*y1.z + x1.w*y1.w;

    #pragma unroll
    for (int m = 1; m < 64; m <<= 1) {
        s1 += __shfl_xor(s1, m);
        s2 += __shfl_xor(s2, m);
        dd += __shfl_xor(dd, m);
    }
    __shared__ float red[3][4];
    if (lane == 0) { red[0][wave] = s1; red[1][wave] = s2; red[2][wave] = dd; }
    __syncthreads();
    s1 = red[0][0] + red[0][1] + red[0][2] + red[0][3];
    s2 = red[1][0] + red[1][1] + red[1][2] + red[1][3];
    dd = red[2][0] + red[2][1] + red[2][2] + red[2][3];

    const float inv1 = rsqrtf(s1), inv2 = rsqrtf(s2);
    if (tid == 0) {
        float p = dd * inv1 * inv2 * INV_T;   // pos in full fp32 precision
        pos[row] = p;
        pos[row + N_ROWS] = p;
    }

    // fp4 encode of (normalized * 64); elem k -> byte k/2, LOW nibble = even k
    const float a = inv1 * SCL4, b = inv2 * SCL4;
    unsigned int pa =  f2fp4(x0.x * a)        | (f2fp4(x0.y * a) << 4)
                    | (f2fp4(x0.z * a) << 8)  | (f2fp4(x0.w * a) << 12)
                    | (f2fp4(x1.x * a) << 16) | (f2fp4(x1.y * a) << 20)
                    | (f2fp4(x1.z * a) << 24) | (f2fp4(x1.w * a) << 28);
    unsigned int pb =  f2fp4(y0.x * b)        | (f2fp4(y0.y * b) << 4)
                    | (f2fp4(y0.z * b) << 8)  | (f2fp4(y0.w * b) << 12)
                    | (f2fp4(y1.x * b) << 16) | (f2fp4(y1.y * b) << 20)
                    | (f2fp4(y1.z * b) << 24) | (f2fp4(y1.w * b) << 28);
    *(unsigned int*)(reps + (size_t)row * RBYTES + tid * 4) = pa;
    *(unsigned int*)(reps + (size_t)(N_ROWS + row) * RBYTES + tid * 4) = pb;
}

// ---------------- kernel 2: triangular S = reps@reps^T, MX-fp4, NO LDS ------
// Barrier-free K-loop: fp4 fragments are 16 B/lane, loaded DIRECTLY from
// global (L1/L2) into registers; the 2 waves sharing a panel hit L1 (16 KB
// working set/iter << 32 KB L1). 1-deep software-pipelined prefetch; compiler
// schedules vmcnt(N) with no barrier coupling. Finalize fused via counter.
__global__ __launch_bounds__(256) void simclr_gemm(
    const unsigned char* __restrict__ reps, float* __restrict__ rowsum,
    const float* __restrict__ pos, int* __restrict__ counter,
    float* __restrict__ out)
{
    // decode linear block id -> lower-triangle (r >= c); bi = c, bj = r
    const int t = blockIdx.x;
    int r = (int)((sqrtf(8.0f * (float)t + 1.0f) - 1.0f) * 0.5f);
    while ((r + 1) * (r + 2) / 2 <= t) ++r;
    while (r * (r + 1) / 2 > t) --r;
    const int bi = t - r * (r + 1) / 2;   // <= bj
    const int bj = r;
    const bool diag = (bi == bj);

    const int tid  = threadIdx.x;
    const int lane = tid & 63, wave = tid >> 6;
    const int wr = wave >> 1, wc = wave & 1;       // 2x2 waves over 128x128
    const int quad = lane >> 4, l16 = lane & 15;
    const int row0 = bi * TILE, col0 = bj * TILE;

    // lane's fragment source: row (wr*64 + fi*16 + l16), bytes quad*16 + i*64
    const unsigned char* Abase =
        reps + (size_t)(row0 + wr * 64 + l16) * RBYTES + quad * 16;
    const unsigned char* Bbase =
        reps + (size_t)(col0 + wc * 64 + l16) * RBYTES + quad * 16;

    floatx4 acc[4][4];
    #pragma unroll
    for (int i = 0; i < 4; ++i)
        #pragma unroll
        for (int j = 0; j < 4; ++j)
            acc[i][j] = floatx4{0.f, 0.f, 0.f, 0.f};

    intx4 a_cur[4], b_cur[4];
    #pragma unroll
    for (int f = 0; f < 4; ++f) {
        a_cur[f] = *(const intx4*)(Abase + (size_t)f * 16 * RBYTES);
        b_cur[f] = *(const intx4*)(Bbase + (size_t)f * 16 * RBYTES);
    }

    #pragma unroll 2
    for (int i = 0; i < NITER; ++i) {
        intx4 a_nxt[4], b_nxt[4];
        if (i + 1 < NITER) {              // prefetch next K-chunk (no barrier)
            const size_t ko = (size_t)(i + 1) * KBYT;
            #pragma unroll
            for (int f = 0; f < 4; ++f) {
                a_nxt[f] = *(const intx4*)(Abase + ko + (size_t)f * 16 * RBYTES);
                b_nxt[f] = *(const intx4*)(Bbase + ko + (size_t)f * 16 * RBYTES);
            }
        }
        #pragma unroll
        for (int fi = 0; fi < 4; ++fi) {
            intx8 aop = intx8{a_cur[fi][0], a_cur[fi][1], a_cur[fi][2], a_cur[fi][3],
                              0, 0, 0, 0};
            #pragma unroll
            for (int j = 0; j < 4; ++j) {
                intx8 bop = intx8{b_cur[j][0], b_cur[j][1], b_cur[j][2], b_cur[j][3],
                                  0, 0, 0, 0};
                acc[fi][j] = __builtin_amdgcn_mfma_scale_f32_16x16x128_f8f6f4(
                    aop, bop, acc[fi][j],
                    4, 4,                      // cbsz=fp4(A), blgp=fp4(B)
                    0, 0x7F7F7F7Fu,            // scale_a = 1.0 (E8M0)
                    0, 0x7F7F7F7Fu);           // scale_b = 1.0
            }
        }
        #pragma unroll
        for (int f = 0; f < 4; ++f) { a_cur[f] = a_nxt[f]; b_cur[f] = b_nxt[f]; }
    }

    // Epilogue: C/D layout col = lane&15, row = quad*4 + reg.
    // logit = acc * INV_T / SCL4^2; |logit| <= 2 so plain exp-sum is safe.
    const float descale = INV_T / (SCL4 * SCL4);   // 1/2048
    float scol[4] = {0.f, 0.f, 0.f, 0.f};
    #pragma unroll
    for (int fi = 0; fi < 4; ++fi) {
        const int rbase = row0 + wr * 64 + fi * 16 + quad * 4;
        float srow[4] = {0.f, 0.f, 0.f, 0.f};
        #pragma unroll
        for (int j = 0; j < 4; ++j) {
            const int c = col0 + wc * 64 + j * 16 + l16;
            #pragma unroll
            for (int rr = 0; rr < 4; ++rr) {
                float e = __expf(acc[fi][j][rr] * descale);
                if (diag && (rbase + rr == c)) e = 0.f;  // exclude self-sim
                srow[rr] += e;
                scol[j]  += e;
            }
        }
        #pragma unroll
        for (int rr = 0; rr < 4; ++rr) {
            #pragma unroll
            for (int m = 1; m < 16; m <<= 1) srow[rr] += __shfl_xor(srow[rr], m);
        }
        if (l16 == 0) {
            #pragma unroll
            for (int rr = 0; rr < 4; ++rr)
                atomicAdd(&rowsum[rbase + rr], srow[rr]);
        }
    }
    if (!diag) {   // symmetry credit: column sums -> mirrored rows
        #pragma unroll
        for (int j = 0; j < 4; ++j) {
            scol[j] += __shfl_xor(scol[j], 16);
            scol[j] += __shfl_xor(scol[j], 32);
        }
        if (quad == 0) {
            #pragma unroll
            for (int j = 0; j < 4; ++j)
                atomicAdd(&rowsum[col0 + wc * 64 + j * 16 + l16], scol[j]);
        }
    }

    // ---- fused finalize: last block computes mean(log(rowsum) - pos) ----
    __syncthreads();             // this block's atomics issued by all waves
    __threadfence();             // device-visible before counter bump
    __shared__ int lastBlock;
    __shared__ float red[4];
    if (tid == 0) lastBlock = (atomicAdd(counter, 1) == NBLK - 1) ? 1 : 0;
    __syncthreads();
    if (lastBlock) {
        float s = 0.f;
        for (int rr = tid; rr < TOT; rr += 256) {
            // device-scope atomic read: coherent view of other XCDs' adds
            float rs = atomicAdd(&rowsum[rr], 0.0f);
            s += logf(rs) - pos[rr];
        }
        #pragma unroll
        for (int m = 1; m < 64; m <<= 1) s += __shfl_xor(s, m);
        if (lane == 0) red[wave] = s;
        __syncthreads();
        if (tid == 0) out[0] = (red[0] + red[1] + red[2] + red[3]) * (1.0f / TOT);
    }
}

extern "C" void kernel_launch(void* const* d_in, const int* in_sizes, int n_in,
                              void* d_out, int out_size, void* d_ws, size_t ws_size,
                              hipStream_t stream)
{
    const float* z1 = (const float*)d_in[0];
    const float* z2 = (const float*)d_in[1];
    float* out = (float*)d_out;

    char* w = (char*)d_ws;
    unsigned char* reps = (unsigned char*)w;                 // 8 MiB fp4 [8192][1024B]
    float* pos    = (float*)(w + (size_t)TOT * RBYTES);      // 32 KiB
    float* rowsum = pos + TOT;                               // 32 KiB
    int*   counter = (int*)(rowsum + TOT);

    normalize_kernel<<<N_ROWS, 256, 0, stream>>>(z1, z2, reps, pos, rowsum, counter);
    simclr_gemm<<<NBLK, 256, 0, stream>>>(reps, rowsum, pos, counter, out);
}

// Round 9
// 369.562 us; speedup vs baseline: 1.1264x; 1.1264x over previous
//
#include <hip/hip_runtime.h>
#include <stdint.h>

#define N_ROWS 4096
#define Z_DIM  2048
#define TOT    8192           // 2N rows of reps
#define TILE   128
#define RBYTES (Z_DIM / 2)    // 1024 B per fp4 row
#define BKE    128            // K elements per iteration
#define KBYT   (BKE / 2)      // 64 B per row per iteration
#define NITER  (Z_DIM / BKE)  // 16
#define NT     (TOT / TILE)   // 64 tile-columns
#define NBLK   (NT * (NT + 1) / 2)   // 2080 triangular blocks
#define INV_T  2.0f           // 1/temperature
#define SCL4   64.0f          // fp4 pre-scale; logits = acc * INV_T / SCL4^2

typedef __attribute__((ext_vector_type(4))) int   intx4;
typedef __attribute__((ext_vector_type(8))) int   intx8;
typedef __attribute__((ext_vector_type(4))) float floatx4;

// branchless f32 -> fp4 e2m1 code (round to nearest level)
__device__ __forceinline__ unsigned int f2fp4(float v) {
    float a = fabsf(v);
    unsigned int c = (a >= 0.25f) + (a >= 0.75f) + (a >= 1.25f) + (a >= 1.75f)
                   + (a >= 2.5f)  + (a >= 3.5f)  + (a >= 5.0f);
    return c | (v < 0.f ? 8u : 0u);
}

#define GLOAD16(g, l)                                                   \
    __builtin_amdgcn_global_load_lds(                                   \
        (const __attribute__((address_space(1))) unsigned int*)(g),     \
        (__attribute__((address_space(3))) unsigned int*)(l), 16, 0, 0)

// ---------------- kernel 1: row-normalize to fp4(e2m1, x64), pos, zero state
__global__ __launch_bounds__(256) void normalize_kernel(
    const float* __restrict__ z1, const float* __restrict__ z2,
    unsigned char* __restrict__ reps, float* __restrict__ pos,
    float* __restrict__ rowsum, int* __restrict__ counter)
{
    const int row  = blockIdx.x;          // 0..4095
    const int tid  = threadIdx.x;         // 0..255, 8 floats each
    const int lane = tid & 63, wave = tid >> 6;

    if (row < TOT / 256) rowsum[row * 256 + tid] = 0.f;   // fold in memset
    if (row == 0 && tid == 0) *counter = 0;

    const float4* p1 = (const float4*)(z1 + (size_t)row * Z_DIM);
    const float4* p2 = (const float4*)(z2 + (size_t)row * Z_DIM);
    float4 x0 = p1[tid * 2], x1 = p1[tid * 2 + 1];
    float4 y0 = p2[tid * 2], y1 = p2[tid * 2 + 1];

    float s1 = x0.x*x0.x + x0.y*x0.y + x0.z*x0.z + x0.w*x0.w
             + x1.x*x1.x + x1.y*x1.y + x1.z*x1.z + x1.w*x1.w;
    float s2 = y0.x*y0.x + y0.y*y0.y + y0.z*y0.z + y0.w*y0.w
             + y1.x*y1.x + y1.y*y1.y + y1.z*y1.z + y1.w*y1.w;
    float dd = x0.x*y0.x + x0.y*y0.y + x0.z*y0.z + x0.w*y0.w
             + x1.x*y1.x + x1.y*y1.y + x1.z*y1.z + x1.w*y1.w;

    #pragma unroll
    for (int m = 1; m < 64; m <<= 1) {
        s1 += __shfl_xor(s1, m);
        s2 += __shfl_xor(s2, m);
        dd += __shfl_xor(dd, m);
    }
    __shared__ float red[3][4];
    if (lane == 0) { red[0][wave] = s1; red[1][wave] = s2; red[2][wave] = dd; }
    __syncthreads();
    s1 = red[0][0] + red[0][1] + red[0][2] + red[0][3];
    s2 = red[1][0] + red[1][1] + red[1][2] + red[1][3];
    dd = red[2][0] + red[2][1] + red[2][2] + red[2][3];

    const float inv1 = rsqrtf(s1), inv2 = rsqrtf(s2);
    if (tid == 0) {
        float p = dd * inv1 * inv2 * INV_T;   // pos in full fp32 precision
        pos[row] = p;
        pos[row + N_ROWS] = p;
    }

    // fp4 encode of (normalized * 64); elem k -> byte k/2, LOW nibble = even k
    const float a = inv1 * SCL4, b = inv2 * SCL4;
    unsigned int pa =  f2fp4(x0.x * a)        | (f2fp4(x0.y * a) << 4)
                    | (f2fp4(x0.z * a) << 8)  | (f2fp4(x0.w * a) << 12)
                    | (f2fp4(x1.x * a) << 16) | (f2fp4(x1.y * a) << 20)
                    | (f2fp4(x1.z * a) << 24) | (f2fp4(x1.w * a) << 28);
    unsigned int pb =  f2fp4(y0.x * b)        | (f2fp4(y0.y * b) << 4)
                    | (f2fp4(y0.z * b) << 8)  | (f2fp4(y0.w * b) << 12)
                    | (f2fp4(y1.x * b) << 16) | (f2fp4(y1.y * b) << 20)
                    | (f2fp4(y1.z * b) << 24) | (f2fp4(y1.w * b) << 28);
    *(unsigned int*)(reps + (size_t)row * RBYTES + tid * 4) = pa;
    *(unsigned int*)(reps + (size_t)(N_ROWS + row) * RBYTES + tid * 4) = pb;
}

// ---------------- kernel 2: triangular S = reps@reps^T, MX-fp4, barrier-free
// Each wave stages its OWN 64-row A-half + B-half (8 KB/iter) via
// global_load_lds into a private dbuf LDS region, then waits with a
// WAVE-LOCAL s_waitcnt vmcnt(8): the 8 just-issued prefetch loads stay in
// flight, the previous iter's 8 are retired (in-order vm retirement).
// NO __syncthreads in the K-loop -> waves fully de-phase and the DMA-write /
// LDS-read / MFMA pipes overlap across the 8 resident waves/CU.
// Panels duplicated per wave pair (2x L2 traffic; L2 has 3x headroom).
// LDS 16B-chunk swizzle: slot = kc ^ (row&3). Finalize fused via counter.
__global__ __launch_bounds__(256) void simclr_gemm(
    const unsigned char* __restrict__ reps, float* __restrict__ rowsum,
    const float* __restrict__ pos, int* __restrict__ counter,
    float* __restrict__ out)
{
    __shared__ __align__(16) unsigned char L[4][2][8192];   // 64 KiB: [wave][buf][A|B]

    // decode linear block id -> lower-triangle (r >= c); bi = c, bj = r
    const int t = blockIdx.x;
    int r = (int)((sqrtf(8.0f * (float)t + 1.0f) - 1.0f) * 0.5f);
    while ((r + 1) * (r + 2) / 2 <= t) ++r;
    while (r * (r + 1) / 2 > t) --r;
    const int bi = t - r * (r + 1) / 2;   // <= bj
    const int bj = r;
    const bool diag = (bi == bj);

    const int tid  = threadIdx.x;
    const int lane = tid & 63, wave = tid >> 6;
    const int wr = wave >> 1, wc = wave & 1;       // 2x2 waves over 128x128
    const int quad = lane >> 4, l16 = lane & 15;
    const int sw   = l16 & 3;                      // read-side XOR swizzle
    const int row0 = bi * TILE, col0 = bj * TILE;

    floatx4 acc[4][4];
    #pragma unroll
    for (int i = 0; i < 4; ++i)
        #pragma unroll
        for (int j = 0; j < 4; ++j)
            acc[i][j] = floatx4{0.f, 0.f, 0.f, 0.f};

    // staging (per wave, per panel): 4 instrs of 64 lanes x 16 B. Instr q,
    // lane: chunk c = q*64+lane -> panel row q*16 + (lane>>2), slot lane&3,
    // global chunk gkc = (lane&3) ^ ((lane>>2)&3)  [q*16 = 0 mod 4].
    const int lrow = lane >> 2;
    const int gkc  = (lane & 3) ^ (lrow & 3);
    const unsigned char* gA = reps + (size_t)(row0 + wr * 64 + lrow) * RBYTES + gkc * 16;
    const unsigned char* gB = reps + (size_t)(col0 + wc * 64 + lrow) * RBYTES + gkc * 16;
    const size_t qstep = (size_t)16 * RBYTES;      // 16 rows per staging instr

    // prologue: iter 0 -> buf 0
    {
        unsigned char* dA = &L[wave][0][lane * 16];
        #pragma unroll
        for (int q = 0; q < 4; ++q) {
            GLOAD16(gA + q * qstep, dA + q * 1024);
            GLOAD16(gB + q * qstep, dA + 4096 + q * 1024);
        }
    }

    for (int i = 0; i < NITER; ++i) {
        const bool pf = (i + 1 < NITER);
        if (pf) {                          // prefetch iter i+1 into buf^1
            const size_t ko = (size_t)(i + 1) * KBYT;
            unsigned char* dA = &L[wave][(i + 1) & 1][lane * 16];
            #pragma unroll
            for (int q = 0; q < 4; ++q) {
                GLOAD16(gA + ko + q * qstep, dA + q * 1024);
                GLOAD16(gB + ko + q * qstep, dA + 4096 + q * 1024);
            }
        }
        // wave-local wait: prev iter's 8 loads retired (8 newest still out)
        if (pf) __builtin_amdgcn_s_waitcnt(0x0F78);   // vmcnt(8)
        else    __builtin_amdgcn_s_waitcnt(0x0F70);   // vmcnt(0)

        const unsigned char* Ab = &L[wave][i & 1][0];
        const unsigned char* Bb = Ab + 4096;

        // fragment: 32 fp4 nibbles (elems k=quad*32..+32) = 16 B = 1 b128
        intx8 af[4], bf[4];
        #pragma unroll
        for (int fi = 0; fi < 4; ++fi) {
            const int ar = (fi * 16 + l16) * KBYT + ((quad ^ sw) << 4);
            intx4 av = *(const intx4*)&Ab[ar];
            intx4 bv = *(const intx4*)&Bb[ar];
            af[fi] = intx8{av[0], av[1], av[2], av[3], 0, 0, 0, 0};
            bf[fi] = intx8{bv[0], bv[1], bv[2], bv[3], 0, 0, 0, 0};
        }
        #pragma unroll
        for (int fi = 0; fi < 4; ++fi)
            #pragma unroll
            for (int j = 0; j < 4; ++j)
                acc[fi][j] = __builtin_amdgcn_mfma_scale_f32_16x16x128_f8f6f4(
                    af[fi], bf[j], acc[fi][j],
                    4, 4,                      // cbsz=fp4(A), blgp=fp4(B)
                    0, 0x7F7F7F7Fu,            // scale_a = 1.0 (E8M0)
                    0, 0x7F7F7F7Fu);           // scale_b = 1.0
    }

    // Epilogue: C/D layout col = lane&15, row = quad*4 + reg.
    // logit = acc * INV_T / SCL4^2; |logit| <= 2 so plain exp-sum is safe.
    const float descale = INV_T / (SCL4 * SCL4);   // 1/2048
    float scol[4] = {0.f, 0.f, 0.f, 0.f};
    #pragma unroll
    for (int fi = 0; fi < 4; ++fi) {
        const int rbase = row0 + wr * 64 + fi * 16 + quad * 4;
        float srow[4] = {0.f, 0.f, 0.f, 0.f};
        #pragma unroll
        for (int j = 0; j < 4; ++j) {
            const int c = col0 + wc * 64 + j * 16 + l16;
            #pragma unroll
            for (int rr = 0; rr < 4; ++rr) {
                float e = __expf(acc[fi][j][rr] * descale);
                if (diag && (rbase + rr == c)) e = 0.f;  // exclude self-sim
                srow[rr] += e;
                scol[j]  += e;
            }
        }
        #pragma unroll
        for (int rr = 0; rr < 4; ++rr) {
            #pragma unroll
            for (int m = 1; m < 16; m <<= 1) srow[rr] += __shfl_xor(srow[rr], m);
        }
        if (l16 == 0) {
            #pragma unroll
            for (int rr = 0; rr < 4; ++rr)
                atomicAdd(&rowsum[rbase + rr], srow[rr]);
        }
    }
    if (!diag) {   // symmetry credit: column sums -> mirrored rows
        #pragma unroll
        for (int j = 0; j < 4; ++j) {
            scol[j] += __shfl_xor(scol[j], 16);
            scol[j] += __shfl_xor(scol[j], 32);
        }
        if (quad == 0) {
            #pragma unroll
            for (int j = 0; j < 4; ++j)
                atomicAdd(&rowsum[col0 + wc * 64 + j * 16 + l16], scol[j]);
        }
    }

    // ---- fused finalize: last block computes mean(log(rowsum) - pos) ----
    __syncthreads();             // this block's atomics issued by all waves
    __threadfence();             // device-visible before counter bump
    __shared__ int lastBlock;
    __shared__ float red[4];
    if (tid == 0) lastBlock = (atomicAdd(counter, 1) == NBLK - 1) ? 1 : 0;
    __syncthreads();
    if (lastBlock) {
        float s = 0.f;
        for (int rr = tid; rr < TOT; rr += 256) {
            // device-scope atomic read: coherent view of other XCDs' adds
            float rs = atomicAdd(&rowsum[rr], 0.0f);
            s += logf(rs) - pos[rr];
        }
        #pragma unroll
        for (int m = 1; m < 64; m <<= 1) s += __shfl_xor(s, m);
        if (lane == 0) red[wave] = s;
        __syncthreads();
        if (tid == 0) out[0] = (red[0] + red[1] + red[2] + red[3]) * (1.0f / TOT);
    }
}

extern "C" void kernel_launch(void* const* d_in, const int* in_sizes, int n_in,
                              void* d_out, int out_size, void* d_ws, size_t ws_size,
                              hipStream_t stream)
{
    const float* z1 = (const float*)d_in[0];
    const float* z2 = (const float*)d_in[1];
    float* out = (float*)d_out;

    char* w = (char*)d_ws;
    unsigned char* reps = (unsigned char*)w;                 // 8 MiB fp4 [8192][1024B]
    float* pos    = (float*)(w + (size_t)TOT * RBYTES);      // 32 KiB
    float* rowsum = pos + TOT;                               // 32 KiB
    int*   counter = (int*)(rowsum + TOT);

    normalize_kernel<<<N_ROWS, 256, 0, stream>>>(z1, z2, reps, pos, rowsum, counter);
    simclr_gemm<<<NBLK, 256, 0, stream>>>(reps, rowsum, pos, counter, out);
}

// Round 10
// 157.213 us; speedup vs baseline: 2.6479x; 2.3507x over previous
//
#include <hip/hip_runtime.h>
#include <stdint.h>

#define N_ROWS 4096
#define Z_DIM  2048
#define TOT    8192           // 2N rows of reps
#define TILE   128
#define RBYTES (Z_DIM / 2)    // 1024 B per fp4 row
#define BKE    256            // K elements per iteration
#define KBYT   (BKE / 2)      // 128 B per row per iteration
#define NITER  (Z_DIM / BKE)  // 8
#define NT     (TOT / TILE)   // 64 tile-columns
#define NBLK   (NT * (NT + 1) / 2)   // 2080 triangular blocks
#define INV_T  2.0f           // 1/temperature
#define SCL4   64.0f          // fp4 pre-scale; logits = acc * INV_T / SCL4^2

typedef __attribute__((ext_vector_type(4))) int   intx4;
typedef __attribute__((ext_vector_type(8))) int   intx8;
typedef __attribute__((ext_vector_type(4))) float floatx4;

// branchless f32 -> fp4 e2m1 code (round to nearest level)
// levels: 0,0.5,1,1.5,2,3,4,6 ; thresholds at midpoints
__device__ __forceinline__ unsigned int f2fp4(float v) {
    float a = fabsf(v);
    unsigned int c = (a >= 0.25f) + (a >= 0.75f) + (a >= 1.25f) + (a >= 1.75f)
                   + (a >= 2.5f)  + (a >= 3.5f)  + (a >= 5.0f);
    return c | (v < 0.f ? 8u : 0u);
}

#define GLOAD16(g, l)                                                   \
    __builtin_amdgcn_global_load_lds(                                   \
        (const __attribute__((address_space(1))) unsigned int*)(g),     \
        (__attribute__((address_space(3))) unsigned int*)(l), 16, 0, 0)

// ---------------- kernel 1: row-normalize to fp4(e2m1, x64), pos, zero rowsum
__global__ __launch_bounds__(256) void normalize_kernel(
    const float* __restrict__ z1, const float* __restrict__ z2,
    unsigned char* __restrict__ reps, float* __restrict__ pos,
    float* __restrict__ rowsum)
{
    const int row  = blockIdx.x;          // 0..4095
    const int tid  = threadIdx.x;         // 0..255, 8 floats each
    const int lane = tid & 63, wave = tid >> 6;

    if (row < TOT / 256) rowsum[row * 256 + tid] = 0.f;   // fold in memset

    const float4* p1 = (const float4*)(z1 + (size_t)row * Z_DIM);
    const float4* p2 = (const float4*)(z2 + (size_t)row * Z_DIM);
    float4 x0 = p1[tid * 2], x1 = p1[tid * 2 + 1];
    float4 y0 = p2[tid * 2], y1 = p2[tid * 2 + 1];

    float s1 = x0.x*x0.x + x0.y*x0.y + x0.z*x0.z + x0.w*x0.w
             + x1.x*x1.x + x1.y*x1.y + x1.z*x1.z + x1.w*x1.w;
    float s2 = y0.x*y0.x + y0.y*y0.y + y0.z*y0.z + y0.w*y0.w
             + y1.x*y1.x + y1.y*y1.y + y1.z*y1.z + y1.w*y1.w;
    float dd = x0.x*y0.x + x0.y*y0.y + x0.z*y0.z + x0.w*y0.w
             + x1.x*y1.x + x1.y*y1.y + x1.z*y1.z + x1.w*y1.w;

    #pragma unroll
    for (int m = 1; m < 64; m <<= 1) {
        s1 += __shfl_xor(s1, m);
        s2 += __shfl_xor(s2, m);
        dd += __shfl_xor(dd, m);
    }
    __shared__ float red[3][4];
    if (lane == 0) { red[0][wave] = s1; red[1][wave] = s2; red[2][wave] = dd; }
    __syncthreads();
    s1 = red[0][0] + red[0][1] + red[0][2] + red[0][3];
    s2 = red[1][0] + red[1][1] + red[1][2] + red[1][3];
    dd = red[2][0] + red[2][1] + red[2][2] + red[2][3];

    const float inv1 = rsqrtf(s1), inv2 = rsqrtf(s2);
    if (tid == 0) {
        float p = dd * inv1 * inv2 * INV_T;   // pos in full fp32 precision
        pos[row] = p;
        pos[row + N_ROWS] = p;
    }

    // fp4 encode of (normalized * 64); elem k -> byte k/2, LOW nibble = even k
    const float a = inv1 * SCL4, b = inv2 * SCL4;
    unsigned int pa =  f2fp4(x0.x * a)        | (f2fp4(x0.y * a) << 4)
                    | (f2fp4(x0.z * a) << 8)  | (f2fp4(x0.w * a) << 12)
                    | (f2fp4(x1.x * a) << 16) | (f2fp4(x1.y * a) << 20)
                    | (f2fp4(x1.z * a) << 24) | (f2fp4(x1.w * a) << 28);
    unsigned int pb =  f2fp4(y0.x * b)        | (f2fp4(y0.y * b) << 4)
                    | (f2fp4(y0.z * b) << 8)  | (f2fp4(y0.w * b) << 12)
                    | (f2fp4(y1.x * b) << 16) | (f2fp4(y1.y * b) << 20)
                    | (f2fp4(y1.z * b) << 24) | (f2fp4(y1.w * b) << 28);
    *(unsigned int*)(reps + (size_t)row * RBYTES + tid * 4) = pa;
    *(unsigned int*)(reps + (size_t)(N_ROWS + row) * RBYTES + tid * 4) = pb;
}

// ---------------- kernel 2: triangular S = reps@reps^T, MX-fp4 K=256 --------
// R7 structure (128x128 tile, 2x2 waves, dbuf + prefetch-before-MFMA, one
// barrier/iter) with BK=256: 8 iters of 32 MFMAs — halves the per-iter
// fixed barrier/drain cost. Each 128-B K-row is stored as TWO 64-B
// sub-panels (K-half h at offset h*8 KB) so the LDS swizzle/conflict
// profile is identical to R7's measured one (slot = kc ^ (row&3) within
// each sub-panel). LDS 64 KB -> 2 blocks/CU (R6-verified non-harmful).
__global__ __launch_bounds__(256) void simclr_gemm(
    const unsigned char* __restrict__ reps, float* __restrict__ rowsum)
{
    // [buf][A|B][ sub-panel h*8192 + row*64 + slot*16 ]
    __shared__ __align__(16) unsigned char L[2][2][16384];   // 64 KiB

    // decode linear block id -> lower-triangle (r >= c); bi = c, bj = r
    const int t = blockIdx.x;
    int r = (int)((sqrtf(8.0f * (float)t + 1.0f) - 1.0f) * 0.5f);
    while ((r + 1) * (r + 2) / 2 <= t) ++r;
    while (r * (r + 1) / 2 > t) --r;
    const int bi = t - r * (r + 1) / 2;   // <= bj
    const int bj = r;
    const bool diag = (bi == bj);

    const int tid  = threadIdx.x;
    const int lane = tid & 63, wave = tid >> 6;
    const int wr = wave >> 1, wc = wave & 1;       // 2x2 waves over 128x128
    const int quad = lane >> 4, l16 = lane & 15;
    const int sw   = l16 & 3;                      // read-side XOR swizzle
    const int row0 = bi * TILE, col0 = bj * TILE;

    floatx4 acc[4][4];
    #pragma unroll
    for (int i = 0; i < 4; ++i)
        #pragma unroll
        for (int j = 0; j < 4; ++j)
            acc[i][j] = floatx4{0.f, 0.f, 0.f, 0.f};

    // staging: 4 rounds of 4 KB per operand per iter. Round p, thread tid:
    //   row   = (p&1)*64 + (tid>>2)
    //   kc    = (p>>1)*4 + ((tid&3) ^ ((tid>>2)&3))     (sub-panel p>>1)
    //   LDS   = p*4096 + tid*16  (= h*8192 + row*64 + slot*16; DMA-contiguous)
    const int r_lo = tid >> 2, slot = tid & 3;
    const unsigned char* gA[4]; const unsigned char* gB[4]; int lofs[4];
    #pragma unroll
    for (int p = 0; p < 4; ++p) {
        const int rw = (p & 1) * 64 + r_lo;
        const int kc = (p >> 1) * 4 + (slot ^ (r_lo & 3));
        gA[p] = reps + (size_t)(row0 + rw) * RBYTES + kc * 16;
        gB[p] = reps + (size_t)(col0 + rw) * RBYTES + kc * 16;
        lofs[p] = p * 4096 + tid * 16;
    }

    // prologue: tile 0 -> buffer 0
    #pragma unroll
    for (int p = 0; p < 4; ++p) GLOAD16(gA[p], &L[0][0][lofs[p]]);
    #pragma unroll
    for (int p = 0; p < 4; ++p) GLOAD16(gB[p], &L[0][1][lofs[p]]);
    __syncthreads();

    for (int i = 0; i < NITER; ++i) {
        if (i + 1 < NITER) {              // prefetch tile i+1 into buf^1
            const size_t ko = (size_t)(i + 1) * KBYT;
            const int buf = (i + 1) & 1;
            #pragma unroll
            for (int p = 0; p < 4; ++p) GLOAD16(gA[p] + ko, &L[buf][0][lofs[p]]);
            #pragma unroll
            for (int p = 0; p < 4; ++p) GLOAD16(gB[p] + ko, &L[buf][1][lofs[p]]);
        }
        const unsigned char* Ab = &L[i & 1][0][0];
        const unsigned char* Bb = &L[i & 1][1][0];

        // fragment (K-half h, frag f): 32 fp4 nibbles = 16 B = 1 b128
        intx8 af[2][4], bf[2][4];
        #pragma unroll
        for (int h = 0; h < 2; ++h) {
            #pragma unroll
            for (int f = 0; f < 4; ++f) {
                const int ra = h * 8192 + (wr * 64 + f * 16 + l16) * 64 + ((quad ^ sw) << 4);
                const int rb = h * 8192 + (wc * 64 + f * 16 + l16) * 64 + ((quad ^ sw) << 4);
                intx4 av = *(const intx4*)&Ab[ra];
                intx4 bv = *(const intx4*)&Bb[rb];
                af[h][f] = intx8{av[0], av[1], av[2], av[3], 0, 0, 0, 0};
                bf[h][f] = intx8{bv[0], bv[1], bv[2], bv[3], 0, 0, 0, 0};
            }
        }
        #pragma unroll
        for (int h = 0; h < 2; ++h)
            #pragma unroll
            for (int fi = 0; fi < 4; ++fi)
                #pragma unroll
                for (int j = 0; j < 4; ++j)
                    acc[fi][j] = __builtin_amdgcn_mfma_scale_f32_16x16x128_f8f6f4(
                        af[h][fi], bf[h][j], acc[fi][j],
                        4, 4,                      // cbsz=fp4(A), blgp=fp4(B)
                        0, 0x7F7F7F7Fu,            // scale_a = 1.0 (E8M0)
                        0, 0x7F7F7F7Fu);           // scale_b = 1.0
        __syncthreads();   // own prefetch vmcnt drained (pre-covered by MFMAs)
    }

    // Epilogue: C/D layout col = lane&15, row = quad*4 + reg.
    // logit = acc * INV_T / SCL4^2; |logit| <= 2 so plain exp-sum is safe.
    const float descale = INV_T / (SCL4 * SCL4);   // 1/2048
    float scol[4] = {0.f, 0.f, 0.f, 0.f};
    #pragma unroll
    for (int fi = 0; fi < 4; ++fi) {
        const int rbase = row0 + wr * 64 + fi * 16 + quad * 4;
        float srow[4] = {0.f, 0.f, 0.f, 0.f};
        #pragma unroll
        for (int j = 0; j < 4; ++j) {
            const int c = col0 + wc * 64 + j * 16 + l16;
            #pragma unroll
            for (int rr = 0; rr < 4; ++rr) {
                float e = __expf(acc[fi][j][rr] * descale);
                if (diag && (rbase + rr == c)) e = 0.f;  // exclude self-sim
                srow[rr] += e;
                scol[j]  += e;
            }
        }
        #pragma unroll
        for (int rr = 0; rr < 4; ++rr) {
            #pragma unroll
            for (int m = 1; m < 16; m <<= 1) srow[rr] += __shfl_xor(srow[rr], m);
        }
        if (l16 == 0) {
            #pragma unroll
            for (int rr = 0; rr < 4; ++rr)
                atomicAdd(&rowsum[rbase + rr], srow[rr]);
        }
    }
    if (!diag) {   // symmetry credit: column sums -> mirrored rows
        #pragma unroll
        for (int j = 0; j < 4; ++j) {
            scol[j] += __shfl_xor(scol[j], 16);
            scol[j] += __shfl_xor(scol[j], 32);
        }
        if (quad == 0) {
            #pragma unroll
            for (int j = 0; j < 4; ++j)
                atomicAdd(&rowsum[col0 + wc * 64 + j * 16 + l16], scol[j]);
        }
    }
}

// ---------------- kernel 3: mean(log(rowsum) - pos) ----------------
__global__ __launch_bounds__(1024) void finalize_kernel(
    const float* __restrict__ rowsum, const float* __restrict__ pos,
    float* __restrict__ out)
{
    const int tid = threadIdx.x;
    const int lane = tid & 63, wave = tid >> 6;
    float s = 0.f;
    for (int r = tid; r < TOT; r += 1024) s += logf(rowsum[r]) - pos[r];
    #pragma unroll
    for (int m = 1; m < 64; m <<= 1) s += __shfl_xor(s, m);
    __shared__ float red[16];
    if (lane == 0) red[wave] = s;
    __syncthreads();
    if (tid == 0) {
        float t = 0.f;
        #pragma unroll
        for (int w = 0; w < 16; ++w) t += red[w];
        out[0] = t * (1.0f / TOT);
    }
}

extern "C" void kernel_launch(void* const* d_in, const int* in_sizes, int n_in,
                              void* d_out, int out_size, void* d_ws, size_t ws_size,
                              hipStream_t stream)
{
    const float* z1 = (const float*)d_in[0];
    const float* z2 = (const float*)d_in[1];
    float* out = (float*)d_out;

    char* w = (char*)d_ws;
    unsigned char* reps = (unsigned char*)w;                 // 8 MiB fp4 [8192][1024B]
    float* pos    = (float*)(w + (size_t)TOT * RBYTES);      // 32 KiB
    float* rowsum = pos + TOT;                               // 32 KiB

    normalize_kernel<<<N_ROWS, 256, 0, stream>>>(z1, z2, reps, pos, rowsum);
    simclr_gemm<<<NBLK, 256, 0, stream>>>(reps, rowsum);
    finalize_kernel<<<1, 1024, 0, stream>>>(rowsum, pos, out);
}